// Round 1
// baseline (2382.190 us; speedup 1.0000x reference)
//
#include <hip/hip_runtime.h>
#include <math.h>

// VectorQuantization: B=8192 rows, N=8192 codes, D=512
// out = [quantized (B*D) | ind (B, as float) | loss (B)]
constexpr int B = 8192, N = 8192, D = 512;
constexpr float EPSF = 1e-20f;
constexpr int ROWS = 16;      // rows per block (4 waves x 4 rows)
constexpr int NT   = 256;     // codebook columns per tile
constexpr int DT   = 16;      // d-chunk per LDS stage
constexpr float SKIP  = 20.0f;  // exp(-20) ~ 2e-9: safely negligible
constexpr float DELTA = 0.05f;  // fp32 argmin trust gap; below -> f64 recheck

// ---------------- prep: cnorm[n], xnorm[b] -------------------------------
__global__ __launch_bounds__(256) void prep_norms(const float* __restrict__ x,
                                                  const float* __restrict__ cb,
                                                  float* __restrict__ cnorm,
                                                  float* __restrict__ xnorm) {
    int wave = threadIdx.x >> 6, lane = threadIdx.x & 63;
    int v = blockIdx.x * 4 + wave;
    const float* src;
    float* dst;
    if (v < N) { src = cb + (size_t)v * D; dst = cnorm + v; }
    else       { int b = v - N; if (b >= B) return; src = x + (size_t)b * D; dst = xnorm + b; }
    const float4* s4 = reinterpret_cast<const float4*>(src) + lane * 2;
    float4 a = s4[0], c = s4[1];
    float s = a.x*a.x + a.y*a.y + a.z*a.z + a.w*a.w
            + c.x*c.x + c.y*c.y + c.z*c.z + c.w*c.w;
    #pragma unroll
    for (int off = 1; off < 64; off <<= 1) s += __shfl_xor(s, off);
    if (lane == 0) *dst = s;
}

// ---------------- main fused kernel --------------------------------------
__global__ __launch_bounds__(256) void vq_main(const float* __restrict__ x,
        const float* __restrict__ cb, const float* __restrict__ u,
        const float* __restrict__ cnorm, const float* __restrict__ xnorm,
        float* __restrict__ out_q, float* __restrict__ out_loss,
        float* __restrict__ m1w, float* __restrict__ m2w, int* __restrict__ i1w) {

    __shared__ float xs[ROWS][D];   // 32 KB
    __shared__ float ct[DT][NT];    // 16 KB, ct[d][n] = cb[nb+n][db+d]

    const int tid  = threadIdx.x;
    const int wave = tid >> 6, lane = tid & 63;
    const int rbase = blockIdx.x * ROWS;
    const int wrow  = rbase + wave * 4;   // this wave's first row

    // stage x rows
    for (int i = tid; i < ROWS * (D / 4); i += 256)
        reinterpret_cast<float4*>(xs)[i] =
            reinterpret_cast<const float4*>(x + (size_t)rbase * D)[i];
    __syncthreads();

    float xn[4];
    #pragma unroll
    for (int r = 0; r < 4; ++r) xn[r] = xnorm[wrow + r];

    // per-row online state (wave-uniform where noted)
    float m[4], denom[4], acc[4][8];            // acc: lane owns d = 8*lane..8*lane+7
    float am1[4], am2[4]; int ai1[4];           // argmin top-2 (wave-uniform)
    #pragma unroll
    for (int r = 0; r < 4; ++r) {
        m[r] = -INFINITY; denom[r] = 0.f;
        am1[r] = INFINITY; am2[r] = INFINITY; ai1[r] = 0;
        #pragma unroll
        for (int k = 0; k < 8; ++k) acc[r][k] = 0.f;
    }

    for (int nb = 0; nb < N; nb += NT) {
        float S[4][4];
        #pragma unroll
        for (int r = 0; r < 4; ++r)
            #pragma unroll
            for (int j = 0; j < 4; ++j) S[r][j] = 0.f;

        for (int db = 0; db < D; db += DT) {
            __syncthreads();
            {   // stage ct (transpose): thread tid = column n, 16 d's
                const float4* src = reinterpret_cast<const float4*>(
                        cb + (size_t)(nb + tid) * D + db);
                float4 a0 = src[0], a1 = src[1], a2 = src[2], a3 = src[3];
                ct[ 0][tid]=a0.x; ct[ 1][tid]=a0.y; ct[ 2][tid]=a0.z; ct[ 3][tid]=a0.w;
                ct[ 4][tid]=a1.x; ct[ 5][tid]=a1.y; ct[ 6][tid]=a1.z; ct[ 7][tid]=a1.w;
                ct[ 8][tid]=a2.x; ct[ 9][tid]=a2.y; ct[10][tid]=a2.z; ct[11][tid]=a2.w;
                ct[12][tid]=a3.x; ct[13][tid]=a3.y; ct[14][tid]=a3.z; ct[15][tid]=a3.w;
            }
            __syncthreads();
            #pragma unroll
            for (int dq = 0; dq < DT / 4; ++dq) {
                float creg[4][4];
                #pragma unroll
                for (int k = 0; k < 4; ++k) {
                    float4 cv = *reinterpret_cast<const float4*>(&ct[dq*4 + k][4*lane]);
                    creg[k][0]=cv.x; creg[k][1]=cv.y; creg[k][2]=cv.z; creg[k][3]=cv.w;
                }
                #pragma unroll
                for (int r = 0; r < 4; ++r) {
                    float4 xv = *reinterpret_cast<const float4*>(&xs[wave*4 + r][db + dq*4]);
                    float xr[4] = {xv.x, xv.y, xv.z, xv.w};
                    #pragma unroll
                    for (int k = 0; k < 4; ++k)
                        #pragma unroll
                        for (int j = 0; j < 4; ++j)
                            S[r][j] = fmaf(xr[k], creg[k][j], S[r][j]);
                }
            }
        }

        // ---- logits, argmin top-2, online softmax for this tile ----
        float4 cn4 = *reinterpret_cast<const float4*>(&cnorm[nb + 4*lane]);
        float cn[4] = {cn4.x, cn4.y, cn4.z, cn4.w};

        float logit[4][4], dist[4][4];
        #pragma unroll
        for (int r = 0; r < 4; ++r) {
            float4 u4 = *reinterpret_cast<const float4*>(
                    &u[(size_t)(wrow + r) * N + nb + 4*lane]);
            float uu[4] = {u4.x, u4.y, u4.z, u4.w};
            #pragma unroll
            for (int j = 0; j < 4; ++j) {
                float ds = xn[r] - 2.f * S[r][j] + cn[j];
                float g  = -logf(-logf(uu[j] + EPSF) + EPSF);
                dist[r][j]  = ds;
                logit[r][j] = g - ds;
            }
        }

        #pragma unroll
        for (int r = 0; r < 4; ++r) {
            // lane-local top-2 of dist (first-index tie rule)
            float l1 = INFINITY, l2 = INFINITY; int li = 0;
            #pragma unroll
            for (int j = 0; j < 4; ++j) {
                float dv = dist[r][j]; int idx = nb + 4*lane + j;
                if (dv < l1)      { l2 = l1; l1 = dv; li = idx; }
                else if (dv < l2) { l2 = dv; }
            }
            // wave butterfly top-2 merge
            #pragma unroll
            for (int off = 1; off < 64; off <<= 1) {
                float o1 = __shfl_xor(l1, off), o2 = __shfl_xor(l2, off);
                int   oi = __shfl_xor(li, off);
                if (o1 < l1 || (o1 == l1 && oi < li)) { l2 = fminf(l1, o2); l1 = o1; li = oi; }
                else                                  { l2 = fminf(o1, l2); }
            }
            if (l1 < am1[r] || (l1 == am1[r] && li < ai1[r])) {
                am2[r] = fminf(am1[r], l2); am1[r] = l1; ai1[r] = li;
            } else {
                am2[r] = fminf(am2[r], l1);
            }

            // tile max of logit
            float lm = fmaxf(fmaxf(logit[r][0], logit[r][1]),
                             fmaxf(logit[r][2], logit[r][3]));
            #pragma unroll
            for (int off = 1; off < 64; off <<= 1) lm = fmaxf(lm, __shfl_xor(lm, off));
            if (lm > m[r]) {
                float s = expf(m[r] - lm);      // -inf -> 0 on first tile
                denom[r] *= s;
                #pragma unroll
                for (int k = 0; k < 8; ++k) acc[r][k] *= s;
                m[r] = lm;
            }

            // weights: per-lane denom partials + skip-filtered accumulation
            float w[4];
            #pragma unroll
            for (int j = 0; j < 4; ++j) {
                float e = logit[r][j] - m[r];
                bool act = e > -SKIP;
                w[j] = act ? expf(e) : 0.f;
                denom[r] += w[j];
            }
            #pragma unroll
            for (int j = 0; j < 4; ++j) {
                unsigned long long mk = __ballot(w[j] > 0.f);
                while (mk) {
                    int L = __ffsll((unsigned long long)mk) - 1;
                    mk &= mk - 1;
                    float wb = __shfl(w[j], L);
                    int nstar = nb + 4*L + j;
                    const float4* crow = reinterpret_cast<const float4*>(
                            cb + (size_t)nstar * D + 8*lane);
                    float4 c0 = crow[0], c1 = crow[1];
                    acc[r][0] = fmaf(wb, c0.x, acc[r][0]);
                    acc[r][1] = fmaf(wb, c0.y, acc[r][1]);
                    acc[r][2] = fmaf(wb, c0.z, acc[r][2]);
                    acc[r][3] = fmaf(wb, c0.w, acc[r][3]);
                    acc[r][4] = fmaf(wb, c1.x, acc[r][4]);
                    acc[r][5] = fmaf(wb, c1.y, acc[r][5]);
                    acc[r][6] = fmaf(wb, c1.z, acc[r][6]);
                    acc[r][7] = fmaf(wb, c1.w, acc[r][7]);
                }
            }
        }
    }

    // ---- finalize ----
    #pragma unroll
    for (int r = 0; r < 4; ++r) {
        float dn = denom[r];
        #pragma unroll
        for (int off = 1; off < 64; off <<= 1) dn += __shfl_xor(dn, off);
        float inv = 1.f / dn;
        int row = wrow + r;
        float q[8]; float ls = 0.f;
        #pragma unroll
        for (int k = 0; k < 8; ++k) {
            q[k] = acc[r][k] * inv;
            float dlt = xs[wave*4 + r][8*lane + k] - q[k];
            ls += dlt * dlt;
        }
        float4 q0 = {q[0], q[1], q[2], q[3]}, q1 = {q[4], q[5], q[6], q[7]};
        float4* o = reinterpret_cast<float4*>(out_q + (size_t)row * D + 8*lane);
        o[0] = q0; o[1] = q1;
        #pragma unroll
        for (int off = 1; off < 64; off <<= 1) ls += __shfl_xor(ls, off);
        if (lane == 0) {
            out_loss[row] = 1.25f * ls;     // (BETA + 1) * ||x - q||^2
            m1w[row] = am1[r]; m2w[row] = am2[r]; i1w[row] = ai1[r];
        }
    }
}

// ---------------- f64 argmin recheck for near-tie rows -------------------
__global__ __launch_bounds__(256) void argmin_fix(const float* __restrict__ x,
        const float* __restrict__ cb, const float* __restrict__ m1w,
        const float* __restrict__ m2w, const int* __restrict__ i1w,
        float* __restrict__ out_ind) {
    int b = blockIdx.x, tid = threadIdx.x;
    if (m2w[b] - m1w[b] >= DELTA) {
        if (tid == 0) out_ind[b] = (float)i1w[b];
        return;
    }
    __shared__ double xsd[D];
    for (int i = tid; i < D; i += 256) xsd[i] = (double)x[(size_t)b * D + i];
    __syncthreads();
    double xn = 0.0;
    for (int d = 0; d < D; ++d) xn += xsd[d] * xsd[d];

    double bestv = 1e300; int besti = N;
    for (int n = tid; n < N; n += 256) {
        const float* c = cb + (size_t)n * D;
        double dot = 0.0, cnn = 0.0;
        for (int d = 0; d < D; ++d) {
            double cd = (double)c[d];
            dot += xsd[d] * cd;
            cnn += cd * cd;
        }
        double dv = xn - 2.0 * dot + cnn;
        if (dv < bestv || (dv == bestv && n < besti)) { bestv = dv; besti = n; }
    }
    __shared__ double rv[256]; __shared__ int ri[256];
    rv[tid] = bestv; ri[tid] = besti;
    __syncthreads();
    for (int s = 128; s > 0; s >>= 1) {
        if (tid < s) {
            if (rv[tid+s] < rv[tid] || (rv[tid+s] == rv[tid] && ri[tid+s] < ri[tid])) {
                rv[tid] = rv[tid+s]; ri[tid] = ri[tid+s];
            }
        }
        __syncthreads();
    }
    if (tid == 0) out_ind[b] = (float)ri[0];
}

// ---------------- host launch --------------------------------------------
extern "C" void kernel_launch(void* const* d_in, const int* in_sizes, int n_in,
                              void* d_out, int out_size, void* d_ws, size_t ws_size,
                              hipStream_t stream) {
    const float* x  = (const float*)d_in[0];
    const float* cb = (const float*)d_in[1];
    const float* u  = (const float*)d_in[2];
    float* out      = (float*)d_out;
    float* out_q    = out;
    float* out_ind  = out + (size_t)B * D;
    float* out_loss = out_ind + B;

    float* ws    = (float*)d_ws;
    float* cnorm = ws;
    float* xnorm = ws + N;
    float* m1w   = xnorm + B;
    float* m2w   = m1w + B;
    int*   i1w   = (int*)(m2w + B);

    hipLaunchKernelGGL(prep_norms, dim3((N + B) / 4), dim3(256), 0, stream,
                       x, cb, cnorm, xnorm);
    hipLaunchKernelGGL(vq_main, dim3(B / ROWS), dim3(256), 0, stream,
                       x, cb, u, cnorm, xnorm, out_q, out_loss, m1w, m2w, i1w);
    hipLaunchKernelGGL(argmin_fix, dim3(B), dim3(256), 0, stream,
                       x, cb, m1w, m2w, i1w, out_ind);
}

// Round 2
// 1557.622 us; speedup vs baseline: 1.5294x; 1.5294x over previous
//
#include <hip/hip_runtime.h>
#include <math.h>

// VectorQuantization: B=8192 rows, N=8192 codes, D=512
// out = [quantized (B*D) | ind (B, as float) | loss (B)]
constexpr int B = 8192, N = 8192, D = 512;
constexpr float EPSF = 1e-20f;
constexpr float SKIP  = 20.0f;  // exp(-20) ~ 2e-9: safely negligible
constexpr float DELTA = 0.05f;  // dist trust gap; below -> f64 recheck
constexpr int CAP = 64;         // candidate list slots per row per half

typedef short bf16x8 __attribute__((ext_vector_type(8)));
typedef float f32x4 __attribute__((ext_vector_type(4)));

__device__ inline unsigned short f2bf(float f) {
    unsigned x = __float_as_uint(f);
    unsigned r = x + 0x7FFFu + ((x >> 16) & 1u);   // RNE, finite inputs
    return (unsigned short)(r >> 16);
}
__device__ inline float bf2f(unsigned short h) {
    return __uint_as_float(((unsigned)h) << 16);
}

// ======================= FAST PATH (MFMA) =================================

// ---- prep: split x/cb into bf16 hi/lo, norms, zero list counts ----------
__global__ __launch_bounds__(256) void vq_prep(const float* __restrict__ x,
        const float* __restrict__ cb,
        unsigned short* __restrict__ xh, unsigned short* __restrict__ xl,
        unsigned short* __restrict__ ch, unsigned short* __restrict__ cl,
        float* __restrict__ cnorm, float* __restrict__ xnorm,
        int* __restrict__ counts) {
    int w = threadIdx.x >> 6, lane = threadIdx.x & 63;
    int gid = blockIdx.x * 256 + threadIdx.x;
    if (gid < 2 * B) counts[gid] = 0;
    int v = blockIdx.x * 4 + w;            // 0..16383
    const float* src; unsigned short *dh, *dl; float* nrm;
    if (v < N) { src = cb + (size_t)v * D; dh = ch + (size_t)v * D; dl = cl + (size_t)v * D; nrm = cnorm + v; }
    else       { int b = v - N; src = x + (size_t)b * D; dh = xh + (size_t)b * D; dl = xl + (size_t)b * D; nrm = xnorm + b; }
    const float4* s4 = reinterpret_cast<const float4*>(src) + lane * 2;
    float4 a = s4[0], c = s4[1];
    float vals[8] = {a.x, a.y, a.z, a.w, c.x, c.y, c.z, c.w};
    float ns = 0.f;
    unsigned short hb[8], lb[8];
    #pragma unroll
    for (int e = 0; e < 8; ++e) {
        float vv = vals[e];
        ns += vv * vv;
        unsigned short h = f2bf(vv);
        float lo = vv - bf2f(h);
        hb[e] = h; lb[e] = f2bf(lo);
    }
    #pragma unroll
    for (int off = 1; off < 64; off <<= 1) ns += __shfl_xor(ns, off);
    if (lane == 0) *nrm = ns;
    *reinterpret_cast<bf16x8*>(dh + lane * 8) = *reinterpret_cast<bf16x8*>(hb);
    *reinterpret_cast<bf16x8*>(dl + lane * 8) = *reinterpret_cast<bf16x8*>(lb);
}

// ---- LDS layout for vq_mfma (bytes) ----
constexpr int BSTRIDE = 1040;              // 512 bf16 + 8 pad (16B aligned, bank-spread)
constexpr int OFF_BH = 0;                  // 64*1040 = 66560
constexpr int OFF_BL = 66560;              // 66560
constexpr int OFF_CN = 133120;             // 256
constexpr int OFF_RM = 133376;             // 256 row running max logit
constexpr int OFF_R1 = 133632;             // 256 row min dist
constexpr int OFF_R2 = 133888;             // 256 row 2nd min dist
constexpr int OFF_RI = 134144;             // 256 row argmin
constexpr int OFF_CT = 134400;             // 256 row list counter
constexpr int OFF_PM = 134656;             // 512 pmax[2][64]
constexpr int OFF_P1 = 135168;             // 512
constexpr int OFF_P2 = 135680;             // 512
constexpr int OFF_PI = 136192;             // 512
constexpr int SMEM_BYTES = 136704;

// ---- main MFMA sweep: grid 256 = 128 row-groups x 2 N-halves ------------
__global__ __launch_bounds__(512, 2) void vq_mfma(
        const unsigned short* __restrict__ xh, const unsigned short* __restrict__ xl,
        const unsigned short* __restrict__ ch, const unsigned short* __restrict__ cl,
        const float* __restrict__ cnorm, const float* __restrict__ xnorm,
        const float* __restrict__ u,
        int2* __restrict__ lists, int* __restrict__ counts,
        float* __restrict__ m1h, float* __restrict__ m2h, int* __restrict__ i1h) {

    __shared__ __align__(16) unsigned char smem[SMEM_BYTES];

    const int tid = threadIdx.x, w = tid >> 6, lane = tid & 63;
    const int wm = w >> 1, wn = w & 1, l15 = lane & 15, g = lane >> 4;
    const int rg = blockIdx.x >> 1, half = blockIdx.x & 1;
    const int rbase = rg * 64, nb0 = half * 4096;

    // A fragments (full K) in registers: rows rbase + wm*16 + l15
    bf16x8 ah[16], al[16];
    {
        const int arow = rbase + wm * 16 + l15;
        const unsigned short* ph = xh + (size_t)arow * D + g * 8;
        const unsigned short* pl = xl + (size_t)arow * D + g * 8;
        #pragma unroll
        for (int ks = 0; ks < 16; ++ks) {
            ah[ks] = *reinterpret_cast<const bf16x8*>(ph + ks * 32);
            al[ks] = *reinterpret_cast<const bf16x8*>(pl + ks * 32);
        }
    }
    float xn_r[4];
    #pragma unroll
    for (int r = 0; r < 4; ++r) xn_r[r] = xnorm[rbase + wm * 16 + g * 4 + r];

    if (tid < 64) {
        *(float*)(smem + OFF_RM + tid * 4) = -INFINITY;
        *(float*)(smem + OFF_R1 + tid * 4) = INFINITY;
        *(float*)(smem + OFF_R2 + tid * 4) = INFINITY;
        *(int*)(smem + OFF_RI + tid * 4) = 0;
        *(int*)(smem + OFF_CT + tid * 4) = 0;
    }

    const int colA = wn * 32 + l15;
    const int vb0 = colA * BSTRIDE + g * 16;            // f=0
    const int vb1 = (colA + 16) * BSTRIDE + g * 16;     // f=1

    #pragma unroll 1
    for (int t = 0; t < 64; ++t) {
        const int nb = nb0 + t * 64;
        // u prefetch (registers; consumed in epilogue)
        float ur[2][4];
        #pragma unroll
        for (int f = 0; f < 2; ++f)
            #pragma unroll
            for (int r = 0; r < 4; ++r)
                ur[f][r] = u[(size_t)(rbase + wm * 16 + g * 4 + r) * N + nb + wn * 32 + f * 16 + l15];

        // stage B tile (64 codes x 512 k, hi+lo)
        {
            const int srow = tid >> 3, seg = tid & 7;
            const unsigned short* sh = ch + (size_t)(nb + srow) * D + seg * 64;
            const unsigned short* sl = cl + (size_t)(nb + srow) * D + seg * 64;
            unsigned char* dh = smem + OFF_BH + srow * BSTRIDE + seg * 128;
            unsigned char* dl = smem + OFF_BL + srow * BSTRIDE + seg * 128;
            #pragma unroll
            for (int i = 0; i < 8; ++i)
                *reinterpret_cast<bf16x8*>(dh + i * 16) = *reinterpret_cast<const bf16x8*>(sh + i * 8);
            #pragma unroll
            for (int i = 0; i < 8; ++i)
                *reinterpret_cast<bf16x8*>(dl + i * 16) = *reinterpret_cast<const bf16x8*>(sl + i * 8);
        }
        if (tid < 64) *(float*)(smem + OFF_CN + tid * 4) = cnorm[nb + tid];
        __syncthreads();   // SYNC_A: staging done (also covers prev admission)

        // GEMM: S = x . c^T (3-product bf16 split)
        f32x4 acc0 = {0.f, 0.f, 0.f, 0.f}, acc1 = {0.f, 0.f, 0.f, 0.f};
        #pragma unroll
        for (int ks = 0; ks < 16; ++ks) {
            bf16x8 b0h = *reinterpret_cast<const bf16x8*>(smem + OFF_BH + vb0 + ks * 64);
            bf16x8 b1h = *reinterpret_cast<const bf16x8*>(smem + OFF_BH + vb1 + ks * 64);
            bf16x8 b0l = *reinterpret_cast<const bf16x8*>(smem + OFF_BL + vb0 + ks * 64);
            bf16x8 b1l = *reinterpret_cast<const bf16x8*>(smem + OFF_BL + vb1 + ks * 64);
            acc0 = __builtin_amdgcn_mfma_f32_16x16x32_bf16(ah[ks], b0h, acc0, 0, 0, 0);
            acc1 = __builtin_amdgcn_mfma_f32_16x16x32_bf16(ah[ks], b1h, acc1, 0, 0, 0);
            acc0 = __builtin_amdgcn_mfma_f32_16x16x32_bf16(ah[ks], b0l, acc0, 0, 0, 0);
            acc1 = __builtin_amdgcn_mfma_f32_16x16x32_bf16(ah[ks], b1l, acc1, 0, 0, 0);
            acc0 = __builtin_amdgcn_mfma_f32_16x16x32_bf16(al[ks], b0h, acc0, 0, 0, 0);
            acc1 = __builtin_amdgcn_mfma_f32_16x16x32_bf16(al[ks], b1h, acc1, 0, 0, 0);
        }

        // epilogue: dist/logit per element; C/D layout row=g*4+r, col=l15
        float cn0 = *(float*)(smem + OFF_CN + (wn * 32 + l15) * 4);
        float cn1 = *(float*)(smem + OFF_CN + (wn * 32 + 16 + l15) * 4);
        float dist[2][4], logit[2][4];
        #pragma unroll
        for (int f = 0; f < 2; ++f) {
            float cnf = f ? cn1 : cn0;
            #pragma unroll
            for (int r = 0; r < 4; ++r) {
                float S = f ? acc1[r] : acc0[r];
                float ds = xn_r[r] - 2.f * S + cnf;
                float gn = -logf(-logf(ur[f][r] + EPSF) + EPSF);
                dist[f][r] = ds; logit[f][r] = gn - ds;
            }
        }
        // per-row partials (reduce over 16 lanes of the group)
        #pragma unroll
        for (int r = 0; r < 4; ++r) {
            int c0 = nb + wn * 32 + l15, c1 = c0 + 16;
            float d1, d2; int i1;
            if (dist[0][r] <= dist[1][r]) { d1 = dist[0][r]; i1 = c0; d2 = dist[1][r]; }
            else                          { d1 = dist[1][r]; i1 = c1; d2 = dist[0][r]; }
            float lm = fmaxf(logit[0][r], logit[1][r]);
            #pragma unroll
            for (int off = 1; off < 16; off <<= 1) {
                float od1 = __shfl_xor(d1, off), od2 = __shfl_xor(d2, off);
                int   oi1 = __shfl_xor(i1, off);
                float olm = __shfl_xor(lm, off);
                lm = fmaxf(lm, olm);
                if (od1 < d1 || (od1 == d1 && oi1 < i1)) { d2 = fminf(d1, od2); d1 = od1; i1 = oi1; }
                else d2 = fminf(od1, d2);
            }
            if (l15 == 0) {
                int rl = wm * 16 + g * 4 + r;
                *(float*)(smem + OFF_PM + (wn * 64 + rl) * 4) = lm;
                *(float*)(smem + OFF_P1 + (wn * 64 + rl) * 4) = d1;
                *(float*)(smem + OFF_P2 + (wn * 64 + rl) * 4) = d2;
                *(int*)(smem + OFF_PI + (wn * 64 + rl) * 4) = i1;
            }
        }
        __syncthreads();   // SYNC_B
        if (tid < 64) {
            float m_old = *(float*)(smem + OFF_RM + tid * 4);
            float pm0 = *(float*)(smem + OFF_PM + tid * 4);
            float pm1 = *(float*)(smem + OFF_PM + (64 + tid) * 4);
            *(float*)(smem + OFF_RM + tid * 4) = fmaxf(m_old, fmaxf(pm0, pm1));
            float a1 = *(float*)(smem + OFF_R1 + tid * 4), a2 = *(float*)(smem + OFF_R2 + tid * 4);
            int ai = *(int*)(smem + OFF_RI + tid * 4);
            float b1 = *(float*)(smem + OFF_P1 + tid * 4), b2 = *(float*)(smem + OFF_P2 + tid * 4);
            int bi = *(int*)(smem + OFF_PI + tid * 4);
            if (b1 < a1) { a2 = fminf(a1, b2); a1 = b1; ai = bi; } else a2 = fminf(b1, a2);
            b1 = *(float*)(smem + OFF_P1 + (64 + tid) * 4); b2 = *(float*)(smem + OFF_P2 + (64 + tid) * 4);
            bi = *(int*)(smem + OFF_PI + (64 + tid) * 4);
            if (b1 < a1) { a2 = fminf(a1, b2); a1 = b1; ai = bi; } else a2 = fminf(b1, a2);
            *(float*)(smem + OFF_R1 + tid * 4) = a1;
            *(float*)(smem + OFF_R2 + tid * 4) = a2;
            *(int*)(smem + OFF_RI + tid * 4) = ai;
        }
        __syncthreads();   // SYNC_C
        // admission: logit within SKIP of running max -> candidate list
        #pragma unroll
        for (int f = 0; f < 2; ++f)
            #pragma unroll
            for (int r = 0; r < 4; ++r) {
                int rl = wm * 16 + g * 4 + r;
                float thr = *(float*)(smem + OFF_RM + rl * 4) - SKIP;
                if (logit[f][r] > thr) {
                    int slot = atomicAdd((int*)(smem + OFF_CT + rl * 4), 1);
                    if (slot < CAP) {
                        int grow = rbase + rl;
                        lists[(size_t)(half * B + grow) * CAP + slot] =
                            make_int2(__float_as_int(logit[f][r]), nb + wn * 32 + f * 16 + l15);
                    }
                }
            }
    }
    __syncthreads();
    if (tid < 64) {
        int hrow = half * B + rbase + tid;
        m1h[hrow] = *(float*)(smem + OFF_R1 + tid * 4);
        m2h[hrow] = *(float*)(smem + OFF_R2 + tid * 4);
        i1h[hrow] = *(int*)(smem + OFF_RI + tid * 4);
        int c = *(int*)(smem + OFF_CT + tid * 4);
        counts[hrow] = c > CAP ? CAP : c;
    }
}

// ---- finalize: softmax over candidate lists -> quantized, loss; merge top2
__global__ __launch_bounds__(256) void vq_finalize(
        const float* __restrict__ cb, const float* __restrict__ x,
        const int2* __restrict__ lists, const int* __restrict__ counts,
        float* __restrict__ m1h, float* __restrict__ m2h, int* __restrict__ i1h,
        float* __restrict__ out_q, float* __restrict__ out_loss) {
    __shared__ int2 ebuf[4][2 * CAP];
    int w = threadIdx.x >> 6, lane = threadIdx.x & 63;
    int row = blockIdx.x * 4 + w;
    int n0 = counts[row];      if (n0 > CAP) n0 = CAP;
    int n1 = counts[B + row];  if (n1 > CAP) n1 = CAP;
    int n = n0 + n1;
    if (lane < n0) ebuf[w][lane] = lists[(size_t)row * CAP + lane];
    if (lane < n1) ebuf[w][n0 + lane] = lists[(size_t)(B + row) * CAP + lane];
    __syncthreads();
    float m = -INFINITY;
    for (int e = lane; e < n; e += 64) m = fmaxf(m, __int_as_float(ebuf[w][e].x));
    #pragma unroll
    for (int off = 1; off < 64; off <<= 1) m = fmaxf(m, __shfl_xor(m, off));
    float denom = 0.f;
    for (int e = lane; e < n; e += 64) denom += __expf(__int_as_float(ebuf[w][e].x) - m);
    #pragma unroll
    for (int off = 1; off < 64; off <<= 1) denom += __shfl_xor(denom, off);
    float q[8] = {0.f, 0.f, 0.f, 0.f, 0.f, 0.f, 0.f, 0.f};
    for (int e = 0; e < n; ++e) {
        int2 ent = ebuf[w][e];
        float wgt = __expf(__int_as_float(ent.x) - m);
        const float4* c4 = reinterpret_cast<const float4*>(cb + (size_t)ent.y * D + lane * 8);
        float4 c0 = c4[0], c1 = c4[1];
        q[0] += wgt * c0.x; q[1] += wgt * c0.y; q[2] += wgt * c0.z; q[3] += wgt * c0.w;
        q[4] += wgt * c1.x; q[5] += wgt * c1.y; q[6] += wgt * c1.z; q[7] += wgt * c1.w;
    }
    float inv = 1.f / denom;
    const float4* x4 = reinterpret_cast<const float4*>(x + (size_t)row * D + lane * 8);
    float4 xa = x4[0], xb = x4[1];
    float xs[8] = {xa.x, xa.y, xa.z, xa.w, xb.x, xb.y, xb.z, xb.w};
    float ls = 0.f;
    #pragma unroll
    for (int k = 0; k < 8; ++k) {
        q[k] *= inv;
        float dlt = xs[k] - q[k];
        ls += dlt * dlt;
    }
    float4 q0 = {q[0], q[1], q[2], q[3]}, q1 = {q[4], q[5], q[6], q[7]};
    float4* o = reinterpret_cast<float4*>(out_q + (size_t)row * D + lane * 8);
    o[0] = q0; o[1] = q1;
    #pragma unroll
    for (int off = 1; off < 64; off <<= 1) ls += __shfl_xor(ls, off);
    if (lane == 0) {
        out_loss[row] = 1.25f * ls;
        // merge half top-2 (half0 indices < half1 indices; ties keep half0)
        float a1 = m1h[row], a2 = m2h[row]; int ai = i1h[row];
        float b1 = m1h[B + row], b2 = m2h[B + row]; int bi = i1h[B + row];
        float mm1, mm2; int mi;
        if (b1 < a1) { mm1 = b1; mi = bi; mm2 = fminf(a1, b2); }
        else         { mm1 = a1; mi = ai; mm2 = fminf(b1, a2); }
        m1h[row] = mm1; m2h[row] = mm2; i1h[row] = mi;
    }
}

// ======================= FALLBACK PATH (round-1, passing) =================
constexpr int ROWS = 16;
constexpr int NT   = 256;
constexpr int DT   = 16;

__global__ __launch_bounds__(256) void prep_norms(const float* __restrict__ x,
                                                  const float* __restrict__ cb,
                                                  float* __restrict__ cnorm,
                                                  float* __restrict__ xnorm) {
    int wave = threadIdx.x >> 6, lane = threadIdx.x & 63;
    int v = blockIdx.x * 4 + wave;
    const float* src;
    float* dst;
    if (v < N) { src = cb + (size_t)v * D; dst = cnorm + v; }
    else       { int b = v - N; if (b >= B) return; src = x + (size_t)b * D; dst = xnorm + b; }
    const float4* s4 = reinterpret_cast<const float4*>(src) + lane * 2;
    float4 a = s4[0], c = s4[1];
    float s = a.x*a.x + a.y*a.y + a.z*a.z + a.w*a.w
            + c.x*c.x + c.y*c.y + c.z*c.z + c.w*c.w;
    #pragma unroll
    for (int off = 1; off < 64; off <<= 1) s += __shfl_xor(s, off);
    if (lane == 0) *dst = s;
}

__global__ __launch_bounds__(256) void vq_main(const float* __restrict__ x,
        const float* __restrict__ cb, const float* __restrict__ u,
        const float* __restrict__ cnorm, const float* __restrict__ xnorm,
        float* __restrict__ out_q, float* __restrict__ out_loss,
        float* __restrict__ m1w, float* __restrict__ m2w, int* __restrict__ i1w) {

    __shared__ float xs[ROWS][D];
    __shared__ float ct[DT][NT];

    const int tid  = threadIdx.x;
    const int wave = tid >> 6, lane = tid & 63;
    const int rbase = blockIdx.x * ROWS;
    const int wrow  = rbase + wave * 4;

    for (int i = tid; i < ROWS * (D / 4); i += 256)
        reinterpret_cast<float4*>(xs)[i] =
            reinterpret_cast<const float4*>(x + (size_t)rbase * D)[i];
    __syncthreads();

    float xn[4];
    #pragma unroll
    for (int r = 0; r < 4; ++r) xn[r] = xnorm[wrow + r];

    float m[4], denom[4], acc[4][8];
    float am1[4], am2[4]; int ai1[4];
    #pragma unroll
    for (int r = 0; r < 4; ++r) {
        m[r] = -INFINITY; denom[r] = 0.f;
        am1[r] = INFINITY; am2[r] = INFINITY; ai1[r] = 0;
        #pragma unroll
        for (int k = 0; k < 8; ++k) acc[r][k] = 0.f;
    }

    for (int nb = 0; nb < N; nb += NT) {
        float S[4][4];
        #pragma unroll
        for (int r = 0; r < 4; ++r)
            #pragma unroll
            for (int j = 0; j < 4; ++j) S[r][j] = 0.f;

        for (int db = 0; db < D; db += DT) {
            __syncthreads();
            {
                const float4* src = reinterpret_cast<const float4*>(
                        cb + (size_t)(nb + tid) * D + db);
                float4 a0 = src[0], a1 = src[1], a2 = src[2], a3 = src[3];
                ct[ 0][tid]=a0.x; ct[ 1][tid]=a0.y; ct[ 2][tid]=a0.z; ct[ 3][tid]=a0.w;
                ct[ 4][tid]=a1.x; ct[ 5][tid]=a1.y; ct[ 6][tid]=a1.z; ct[ 7][tid]=a1.w;
                ct[ 8][tid]=a2.x; ct[ 9][tid]=a2.y; ct[10][tid]=a2.z; ct[11][tid]=a2.w;
                ct[12][tid]=a3.x; ct[13][tid]=a3.y; ct[14][tid]=a3.z; ct[15][tid]=a3.w;
            }
            __syncthreads();
            #pragma unroll
            for (int dq = 0; dq < DT / 4; ++dq) {
                float creg[4][4];
                #pragma unroll
                for (int k = 0; k < 4; ++k) {
                    float4 cv = *reinterpret_cast<const float4*>(&ct[dq*4 + k][4*lane]);
                    creg[k][0]=cv.x; creg[k][1]=cv.y; creg[k][2]=cv.z; creg[k][3]=cv.w;
                }
                #pragma unroll
                for (int r = 0; r < 4; ++r) {
                    float4 xv = *reinterpret_cast<const float4*>(&xs[wave*4 + r][db + dq*4]);
                    float xr[4] = {xv.x, xv.y, xv.z, xv.w};
                    #pragma unroll
                    for (int k = 0; k < 4; ++k)
                        #pragma unroll
                        for (int j = 0; j < 4; ++j)
                            S[r][j] = fmaf(xr[k], creg[k][j], S[r][j]);
                }
            }
        }

        float4 cn4 = *reinterpret_cast<const float4*>(&cnorm[nb + 4*lane]);
        float cn[4] = {cn4.x, cn4.y, cn4.z, cn4.w};

        float logit[4][4], dist[4][4];
        #pragma unroll
        for (int r = 0; r < 4; ++r) {
            float4 u4 = *reinterpret_cast<const float4*>(
                    &u[(size_t)(wrow + r) * N + nb + 4*lane]);
            float uu[4] = {u4.x, u4.y, u4.z, u4.w};
            #pragma unroll
            for (int j = 0; j < 4; ++j) {
                float ds = xn[r] - 2.f * S[r][j] + cn[j];
                float g  = -logf(-logf(uu[j] + EPSF) + EPSF);
                dist[r][j]  = ds;
                logit[r][j] = g - ds;
            }
        }

        #pragma unroll
        for (int r = 0; r < 4; ++r) {
            float l1 = INFINITY, l2 = INFINITY; int li = 0;
            #pragma unroll
            for (int j = 0; j < 4; ++j) {
                float dv = dist[r][j]; int idx = nb + 4*lane + j;
                if (dv < l1)      { l2 = l1; l1 = dv; li = idx; }
                else if (dv < l2) { l2 = dv; }
            }
            #pragma unroll
            for (int off = 1; off < 64; off <<= 1) {
                float o1 = __shfl_xor(l1, off), o2 = __shfl_xor(l2, off);
                int   oi = __shfl_xor(li, off);
                if (o1 < l1 || (o1 == l1 && oi < li)) { l2 = fminf(l1, o2); l1 = o1; li = oi; }
                else                                  { l2 = fminf(o1, l2); }
            }
            if (l1 < am1[r] || (l1 == am1[r] && li < ai1[r])) {
                am2[r] = fminf(am1[r], l2); am1[r] = l1; ai1[r] = li;
            } else {
                am2[r] = fminf(am2[r], l1);
            }

            float lm = fmaxf(fmaxf(logit[r][0], logit[r][1]),
                             fmaxf(logit[r][2], logit[r][3]));
            #pragma unroll
            for (int off = 1; off < 64; off <<= 1) lm = fmaxf(lm, __shfl_xor(lm, off));
            if (lm > m[r]) {
                float s = expf(m[r] - lm);
                denom[r] *= s;
                #pragma unroll
                for (int k = 0; k < 8; ++k) acc[r][k] *= s;
                m[r] = lm;
            }

            float wv[4];
            #pragma unroll
            for (int j = 0; j < 4; ++j) {
                float e = logit[r][j] - m[r];
                bool act = e > -SKIP;
                wv[j] = act ? expf(e) : 0.f;
                denom[r] += wv[j];
            }
            #pragma unroll
            for (int j = 0; j < 4; ++j) {
                unsigned long long mk = __ballot(wv[j] > 0.f);
                while (mk) {
                    int L = __ffsll((unsigned long long)mk) - 1;
                    mk &= mk - 1;
                    float wb = __shfl(wv[j], L);
                    int nstar = nb + 4*L + j;
                    const float4* crow = reinterpret_cast<const float4*>(
                            cb + (size_t)nstar * D + 8*lane);
                    float4 c0 = crow[0], c1 = crow[1];
                    acc[r][0] = fmaf(wb, c0.x, acc[r][0]);
                    acc[r][1] = fmaf(wb, c0.y, acc[r][1]);
                    acc[r][2] = fmaf(wb, c0.z, acc[r][2]);
                    acc[r][3] = fmaf(wb, c0.w, acc[r][3]);
                    acc[r][4] = fmaf(wb, c1.x, acc[r][4]);
                    acc[r][5] = fmaf(wb, c1.y, acc[r][5]);
                    acc[r][6] = fmaf(wb, c1.z, acc[r][6]);
                    acc[r][7] = fmaf(wb, c1.w, acc[r][7]);
                }
            }
        }
    }

    #pragma unroll
    for (int r = 0; r < 4; ++r) {
        float dn = denom[r];
        #pragma unroll
        for (int off = 1; off < 64; off <<= 1) dn += __shfl_xor(dn, off);
        float inv = 1.f / dn;
        int row = wrow + r;
        float q[8]; float ls = 0.f;
        #pragma unroll
        for (int k = 0; k < 8; ++k) {
            q[k] = acc[r][k] * inv;
            float dlt = xs[wave*4 + r][8*lane + k] - q[k];
            ls += dlt * dlt;
        }
        float4 q0 = {q[0], q[1], q[2], q[3]}, q1 = {q[4], q[5], q[6], q[7]};
        float4* o = reinterpret_cast<float4*>(out_q + (size_t)row * D + 8*lane);
        o[0] = q0; o[1] = q1;
        #pragma unroll
        for (int off = 1; off < 64; off <<= 1) ls += __shfl_xor(ls, off);
        if (lane == 0) {
            out_loss[row] = 1.25f * ls;
            m1w[row] = am1[r]; m2w[row] = am2[r]; i1w[row] = ai1[r];
        }
    }
}

// ---- f64 argmin recheck for near-tie rows (shared by both paths) --------
__global__ __launch_bounds__(256) void argmin_fix(const float* __restrict__ x,
        const float* __restrict__ cb, const float* __restrict__ m1w,
        const float* __restrict__ m2w, const int* __restrict__ i1w,
        float* __restrict__ out_ind) {
    int b = blockIdx.x, tid = threadIdx.x;
    if (m2w[b] - m1w[b] >= DELTA) {
        if (tid == 0) out_ind[b] = (float)i1w[b];
        return;
    }
    __shared__ double xsd[D];
    for (int i = tid; i < D; i += 256) xsd[i] = (double)x[(size_t)b * D + i];
    __syncthreads();
    double xn = 0.0;
    for (int d = 0; d < D; ++d) xn += xsd[d] * xsd[d];

    double bestv = 1e300; int besti = N;
    for (int n = tid; n < N; n += 256) {
        const float* c = cb + (size_t)n * D;
        double d0 = 0.0, d1v = 0.0, c0 = 0.0, c1v = 0.0;
        for (int d = 0; d < D; d += 2) {
            double ca = (double)c[d], cbv = (double)c[d + 1];
            d0 += xsd[d] * ca;  c0 += ca * ca;
            d1v += xsd[d + 1] * cbv; c1v += cbv * cbv;
        }
        double dv = xn - 2.0 * (d0 + d1v) + (c0 + c1v);
        if (dv < bestv || (dv == bestv && n < besti)) { bestv = dv; besti = n; }
    }
    __shared__ double rv[256]; __shared__ int ri[256];
    rv[tid] = bestv; ri[tid] = besti;
    __syncthreads();
    for (int s = 128; s > 0; s >>= 1) {
        if (tid < s) {
            if (rv[tid+s] < rv[tid] || (rv[tid+s] == rv[tid] && ri[tid+s] < ri[tid])) {
                rv[tid] = rv[tid+s]; ri[tid] = ri[tid+s];
            }
        }
        __syncthreads();
    }
    if (tid == 0) out_ind[b] = (float)ri[0];
}

// ---------------- host launch --------------------------------------------
extern "C" void kernel_launch(void* const* d_in, const int* in_sizes, int n_in,
                              void* d_out, int out_size, void* d_ws, size_t ws_size,
                              hipStream_t stream) {
    const float* x  = (const float*)d_in[0];
    const float* cb = (const float*)d_in[1];
    const float* u  = (const float*)d_in[2];
    float* out      = (float*)d_out;
    float* out_q    = out;
    float* out_ind  = out + (size_t)B * D;
    float* out_loss = out_ind + B;

    // fast-path workspace layout (bytes)
    const size_t O_XH = 0;
    const size_t O_XL = O_XH + (size_t)B * D * 2;          // 8388608
    const size_t O_CH = O_XL + (size_t)B * D * 2;          // 16777216
    const size_t O_CL = O_CH + (size_t)N * D * 2;          // 25165824
    const size_t O_CN = O_CL + (size_t)N * D * 2;          // 33554432
    const size_t O_XN = O_CN + (size_t)N * 4;              // 33587200
    const size_t O_M1 = O_XN + (size_t)B * 4;              // 33619968
    const size_t O_M2 = O_M1 + (size_t)2 * B * 4;          // +65536
    const size_t O_I1 = O_M2 + (size_t)2 * B * 4;
    const size_t O_CT = O_I1 + (size_t)2 * B * 4;
    const size_t O_LS = O_CT + (size_t)2 * B * 4;
    const size_t NEED = O_LS + (size_t)2 * B * CAP * 8;    // 42270720

    if (ws_size >= NEED) {
        char* w8 = (char*)d_ws;
        unsigned short* xh = (unsigned short*)(w8 + O_XH);
        unsigned short* xl = (unsigned short*)(w8 + O_XL);
        unsigned short* ch = (unsigned short*)(w8 + O_CH);
        unsigned short* cl = (unsigned short*)(w8 + O_CL);
        float* cnorm = (float*)(w8 + O_CN);
        float* xnorm = (float*)(w8 + O_XN);
        float* m1h   = (float*)(w8 + O_M1);
        float* m2h   = (float*)(w8 + O_M2);
        int*   i1h   = (int*)(w8 + O_I1);
        int*   counts= (int*)(w8 + O_CT);
        int2*  lists = (int2*)(w8 + O_LS);

        hipLaunchKernelGGL(vq_prep, dim3((N + B) / 4), dim3(256), 0, stream,
                           x, cb, xh, xl, ch, cl, cnorm, xnorm, counts);
        hipLaunchKernelGGL(vq_mfma, dim3(256), dim3(512), 0, stream,
                           xh, xl, ch, cl, cnorm, xnorm, u, lists, counts, m1h, m2h, i1h);
        hipLaunchKernelGGL(vq_finalize, dim3(B / 4), dim3(256), 0, stream,
                           cb, x, lists, counts, m1h, m2h, i1h, out_q, out_loss);
        hipLaunchKernelGGL(argmin_fix, dim3(B), dim3(256), 0, stream,
                           x, cb, m1h, m2h, i1h, out_ind);
    } else {
        float* ws    = (float*)d_ws;
        float* cnorm = ws;
        float* xnorm = ws + N;
        float* m1w   = xnorm + B;
        float* m2w   = m1w + B;
        int*   i1w   = (int*)(m2w + B);

        hipLaunchKernelGGL(prep_norms, dim3((N + B) / 4), dim3(256), 0, stream,
                           x, cb, cnorm, xnorm);
        hipLaunchKernelGGL(vq_main, dim3(B / ROWS), dim3(256), 0, stream,
                           x, cb, u, cnorm, xnorm, out_q, out_loss, m1w, m2w, i1w);
        hipLaunchKernelGGL(argmin_fix, dim3(B), dim3(256), 0, stream,
                           x, cb, m1w, m2w, i1w, out_ind);
    }
}

// Round 3
// 934.733 us; speedup vs baseline: 2.5485x; 1.6664x over previous
//
#include <hip/hip_runtime.h>
#include <math.h>

// VectorQuantization: B=8192 rows, N=8192 codes, D=512
// out = [quantized (B*D) | ind (B, as float) | loss (B)]
constexpr int B = 8192, N = 8192, D = 512;
constexpr float EPSF = 1e-20f;
constexpr float SKIP  = 20.0f;  // exp(-20) ~ 2e-9: safely negligible
constexpr float DELTA = 0.05f;  // dist trust gap; below -> f64 recheck
constexpr int CAP  = 64;        // logit candidate slots per row per half
constexpr int DCAP = 16;        // dist candidate slots per row per half

typedef short bf16x8 __attribute__((ext_vector_type(8)));
typedef float f32x4 __attribute__((ext_vector_type(4)));

__device__ inline unsigned short f2bf(float f) {
    unsigned x = __float_as_uint(f);
    unsigned r = x + 0x7FFFu + ((x >> 16) & 1u);   // RNE, finite inputs
    return (unsigned short)(r >> 16);
}
__device__ inline float bf2f(unsigned short h) {
    return __uint_as_float(((unsigned)h) << 16);
}

// ======================= FAST PATH (MFMA) =================================

// ---- prep: split x/cb into bf16 hi/lo, norms, zero list counts ----------
__global__ __launch_bounds__(256) void vq_prep(const float* __restrict__ x,
        const float* __restrict__ cb,
        unsigned short* __restrict__ xh, unsigned short* __restrict__ xl,
        unsigned short* __restrict__ ch, unsigned short* __restrict__ cl,
        float* __restrict__ cnorm, float* __restrict__ xnorm,
        int* __restrict__ counts, int* __restrict__ dcounts) {
    int w = threadIdx.x >> 6, lane = threadIdx.x & 63;
    int gid = blockIdx.x * 256 + threadIdx.x;
    if (gid < 2 * B) {
        counts[gid] = 0;
        if (dcounts) dcounts[gid] = 0;
    }
    int v = blockIdx.x * 4 + w;            // 0..16383
    const float* src; unsigned short *dh, *dl; float* nrm;
    if (v < N) { src = cb + (size_t)v * D; dh = ch + (size_t)v * D; dl = cl + (size_t)v * D; nrm = cnorm + v; }
    else       { int b = v - N; src = x + (size_t)b * D; dh = xh + (size_t)b * D; dl = xl + (size_t)b * D; nrm = xnorm + b; }
    const float4* s4 = reinterpret_cast<const float4*>(src) + lane * 2;
    float4 a = s4[0], c = s4[1];
    float vals[8] = {a.x, a.y, a.z, a.w, c.x, c.y, c.z, c.w};
    float ns = 0.f;
    unsigned short hb[8], lb[8];
    #pragma unroll
    for (int e = 0; e < 8; ++e) {
        float vv = vals[e];
        ns += vv * vv;
        unsigned short h = f2bf(vv);
        float lo = vv - bf2f(h);
        hb[e] = h; lb[e] = f2bf(lo);
    }
    #pragma unroll
    for (int off = 1; off < 64; off <<= 1) ns += __shfl_xor(ns, off);
    if (lane == 0) *nrm = ns;
    *reinterpret_cast<bf16x8*>(dh + lane * 8) = *reinterpret_cast<bf16x8*>(hb);
    *reinterpret_cast<bf16x8*>(dl + lane * 8) = *reinterpret_cast<bf16x8*>(lb);
}

// ---- LDS layout for vq_mfma (bytes) ----
constexpr int BSTRIDE = 1040;              // 512 bf16 + 8 pad (16B aligned, bank-spread)
constexpr int OFF_BH = 0;                  // 64*1040 = 66560
constexpr int OFF_BL = 66560;              // 66560
constexpr int OFF_CN = 133120;             // 256
constexpr int OFF_RM = 133376;             // 256 row running max logit
constexpr int OFF_R1 = 133632;             // 256 row min dist
constexpr int OFF_R2 = 133888;             // 256 row 2nd min dist
constexpr int OFF_RI = 134144;             // 256 row argmin
constexpr int OFF_CT = 134400;             // 256 row list counter
constexpr int OFF_PM = 134656;             // 512 pmax[2][64]
constexpr int OFF_P1 = 135168;             // 512
constexpr int OFF_P2 = 135680;             // 512
constexpr int OFF_PI = 136192;             // 512
constexpr int OFF_DC = 136704;             // 256 row dist-candidate counter
constexpr int SMEM_BYTES = 136960;

// ---- main MFMA sweep: grid 256 = 128 row-groups x 2 N-halves ------------
__global__ __launch_bounds__(512, 2) void vq_mfma(
        const unsigned short* __restrict__ xh, const unsigned short* __restrict__ xl,
        const unsigned short* __restrict__ ch, const unsigned short* __restrict__ cl,
        const float* __restrict__ cnorm, const float* __restrict__ xnorm,
        const float* __restrict__ u,
        int2* __restrict__ lists, int* __restrict__ counts,
        int* __restrict__ dlists, int* __restrict__ dcounts,
        float* __restrict__ m1h, float* __restrict__ m2h, int* __restrict__ i1h) {

    __shared__ __align__(16) unsigned char smem[SMEM_BYTES];

    const int tid = threadIdx.x, w = tid >> 6, lane = tid & 63;
    const int wm = w >> 1, wn = w & 1, l15 = lane & 15, g = lane >> 4;
    const int rg = blockIdx.x >> 1, half = blockIdx.x & 1;
    const int rbase = rg * 64, nb0 = half * 4096;

    // A fragments (full K) in registers: rows rbase + wm*16 + l15
    bf16x8 ah[16], al[16];
    {
        const int arow = rbase + wm * 16 + l15;
        const unsigned short* ph = xh + (size_t)arow * D + g * 8;
        const unsigned short* pl = xl + (size_t)arow * D + g * 8;
        #pragma unroll
        for (int ks = 0; ks < 16; ++ks) {
            ah[ks] = *reinterpret_cast<const bf16x8*>(ph + ks * 32);
            al[ks] = *reinterpret_cast<const bf16x8*>(pl + ks * 32);
        }
    }
    float xn_r[4];
    #pragma unroll
    for (int r = 0; r < 4; ++r) xn_r[r] = xnorm[rbase + wm * 16 + g * 4 + r];

    if (tid < 64) {
        *(float*)(smem + OFF_RM + tid * 4) = -INFINITY;
        *(float*)(smem + OFF_R1 + tid * 4) = INFINITY;
        *(float*)(smem + OFF_R2 + tid * 4) = INFINITY;
        *(int*)(smem + OFF_RI + tid * 4) = 0;
        *(int*)(smem + OFF_CT + tid * 4) = 0;
        *(int*)(smem + OFF_DC + tid * 4) = 0;
    }

    const int colA = wn * 32 + l15;
    const int vb0 = colA * BSTRIDE + g * 16;            // f=0
    const int vb1 = (colA + 16) * BSTRIDE + g * 16;     // f=1

    #pragma unroll 1
    for (int t = 0; t < 64; ++t) {
        const int nb = nb0 + t * 64;
        // u prefetch (registers; consumed in epilogue)
        float ur[2][4];
        #pragma unroll
        for (int f = 0; f < 2; ++f)
            #pragma unroll
            for (int r = 0; r < 4; ++r)
                ur[f][r] = u[(size_t)(rbase + wm * 16 + g * 4 + r) * N + nb + wn * 32 + f * 16 + l15];

        // stage B tile (64 codes x 512 k, hi+lo)
        {
            const int srow = tid >> 3, seg = tid & 7;
            const unsigned short* sh = ch + (size_t)(nb + srow) * D + seg * 64;
            const unsigned short* sl = cl + (size_t)(nb + srow) * D + seg * 64;
            unsigned char* dh = smem + OFF_BH + srow * BSTRIDE + seg * 128;
            unsigned char* dl = smem + OFF_BL + srow * BSTRIDE + seg * 128;
            #pragma unroll
            for (int i = 0; i < 8; ++i)
                *reinterpret_cast<bf16x8*>(dh + i * 16) = *reinterpret_cast<const bf16x8*>(sh + i * 8);
            #pragma unroll
            for (int i = 0; i < 8; ++i)
                *reinterpret_cast<bf16x8*>(dl + i * 16) = *reinterpret_cast<const bf16x8*>(sl + i * 8);
        }
        if (tid < 64) *(float*)(smem + OFF_CN + tid * 4) = cnorm[nb + tid];
        __syncthreads();   // SYNC_A: staging done (also covers prev admission)

        // GEMM: S = x . c^T (3-product bf16 split)
        f32x4 acc0 = {0.f, 0.f, 0.f, 0.f}, acc1 = {0.f, 0.f, 0.f, 0.f};
        #pragma unroll
        for (int ks = 0; ks < 16; ++ks) {
            bf16x8 b0h = *reinterpret_cast<const bf16x8*>(smem + OFF_BH + vb0 + ks * 64);
            bf16x8 b1h = *reinterpret_cast<const bf16x8*>(smem + OFF_BH + vb1 + ks * 64);
            bf16x8 b0l = *reinterpret_cast<const bf16x8*>(smem + OFF_BL + vb0 + ks * 64);
            bf16x8 b1l = *reinterpret_cast<const bf16x8*>(smem + OFF_BL + vb1 + ks * 64);
            acc0 = __builtin_amdgcn_mfma_f32_16x16x32_bf16(ah[ks], b0h, acc0, 0, 0, 0);
            acc1 = __builtin_amdgcn_mfma_f32_16x16x32_bf16(ah[ks], b1h, acc1, 0, 0, 0);
            acc0 = __builtin_amdgcn_mfma_f32_16x16x32_bf16(ah[ks], b0l, acc0, 0, 0, 0);
            acc1 = __builtin_amdgcn_mfma_f32_16x16x32_bf16(ah[ks], b1l, acc1, 0, 0, 0);
            acc0 = __builtin_amdgcn_mfma_f32_16x16x32_bf16(al[ks], b0h, acc0, 0, 0, 0);
            acc1 = __builtin_amdgcn_mfma_f32_16x16x32_bf16(al[ks], b1h, acc1, 0, 0, 0);
        }

        // epilogue: dist/logit per element; C/D layout row=g*4+r, col=l15
        float cn0 = *(float*)(smem + OFF_CN + (wn * 32 + l15) * 4);
        float cn1 = *(float*)(smem + OFF_CN + (wn * 32 + 16 + l15) * 4);
        float dist[2][4], logit[2][4];
        #pragma unroll
        for (int f = 0; f < 2; ++f) {
            float cnf = f ? cn1 : cn0;
            #pragma unroll
            for (int r = 0; r < 4; ++r) {
                float S = f ? acc1[r] : acc0[r];
                float ds = xn_r[r] - 2.f * S + cnf;
                float gn = -logf(-logf(ur[f][r] + EPSF) + EPSF);
                dist[f][r] = ds; logit[f][r] = gn - ds;
            }
        }
        // per-row partials (reduce over 16 lanes of the group)
        #pragma unroll
        for (int r = 0; r < 4; ++r) {
            int c0 = nb + wn * 32 + l15, c1 = c0 + 16;
            float d1, d2; int i1;
            if (dist[0][r] <= dist[1][r]) { d1 = dist[0][r]; i1 = c0; d2 = dist[1][r]; }
            else                          { d1 = dist[1][r]; i1 = c1; d2 = dist[0][r]; }
            float lm = fmaxf(logit[0][r], logit[1][r]);
            #pragma unroll
            for (int off = 1; off < 16; off <<= 1) {
                float od1 = __shfl_xor(d1, off), od2 = __shfl_xor(d2, off);
                int   oi1 = __shfl_xor(i1, off);
                float olm = __shfl_xor(lm, off);
                lm = fmaxf(lm, olm);
                if (od1 < d1 || (od1 == d1 && oi1 < i1)) { d2 = fminf(d1, od2); d1 = od1; i1 = oi1; }
                else d2 = fminf(od1, d2);
            }
            if (l15 == 0) {
                int rl = wm * 16 + g * 4 + r;
                *(float*)(smem + OFF_PM + (wn * 64 + rl) * 4) = lm;
                *(float*)(smem + OFF_P1 + (wn * 64 + rl) * 4) = d1;
                *(float*)(smem + OFF_P2 + (wn * 64 + rl) * 4) = d2;
                *(int*)(smem + OFF_PI + (wn * 64 + rl) * 4) = i1;
            }
        }
        __syncthreads();   // SYNC_B
        if (tid < 64) {
            float m_old = *(float*)(smem + OFF_RM + tid * 4);
            float pm0 = *(float*)(smem + OFF_PM + tid * 4);
            float pm1 = *(float*)(smem + OFF_PM + (64 + tid) * 4);
            *(float*)(smem + OFF_RM + tid * 4) = fmaxf(m_old, fmaxf(pm0, pm1));
            float a1 = *(float*)(smem + OFF_R1 + tid * 4), a2 = *(float*)(smem + OFF_R2 + tid * 4);
            int ai = *(int*)(smem + OFF_RI + tid * 4);
            float b1 = *(float*)(smem + OFF_P1 + tid * 4), b2 = *(float*)(smem + OFF_P2 + tid * 4);
            int bi = *(int*)(smem + OFF_PI + tid * 4);
            if (b1 < a1) { a2 = fminf(a1, b2); a1 = b1; ai = bi; } else a2 = fminf(b1, a2);
            b1 = *(float*)(smem + OFF_P1 + (64 + tid) * 4); b2 = *(float*)(smem + OFF_P2 + (64 + tid) * 4);
            bi = *(int*)(smem + OFF_PI + (64 + tid) * 4);
            if (b1 < a1) { a2 = fminf(a1, b2); a1 = b1; ai = bi; } else a2 = fminf(b1, a2);
            *(float*)(smem + OFF_R1 + tid * 4) = a1;
            *(float*)(smem + OFF_R2 + tid * 4) = a2;
            *(int*)(smem + OFF_RI + tid * 4) = ai;
        }
        __syncthreads();   // SYNC_C
        // admission: logit within SKIP of running max -> candidate list;
        //            dist within DELTA of running min -> dist-candidate list
        #pragma unroll
        for (int f = 0; f < 2; ++f)
            #pragma unroll
            for (int r = 0; r < 4; ++r) {
                int rl = wm * 16 + g * 4 + r;
                int grow = rbase + rl;
                int cidx = nb + wn * 32 + f * 16 + l15;
                float thr = *(float*)(smem + OFF_RM + rl * 4) - SKIP;
                if (logit[f][r] > thr) {
                    int slot = atomicAdd((int*)(smem + OFF_CT + rl * 4), 1);
                    if (slot < CAP) {
                        lists[(size_t)(half * B + grow) * CAP + slot] =
                            make_int2(__float_as_int(logit[f][r]), cidx);
                    }
                }
                if (dlists) {
                    float r1v = *(float*)(smem + OFF_R1 + rl * 4);
                    if (dist[f][r] < r1v + DELTA) {
                        int slot = atomicAdd((int*)(smem + OFF_DC + rl * 4), 1);
                        if (slot < DCAP)
                            dlists[(size_t)(half * B + grow) * DCAP + slot] = cidx;
                    }
                }
            }
    }
    __syncthreads();
    if (tid < 64) {
        int hrow = half * B + rbase + tid;
        m1h[hrow] = *(float*)(smem + OFF_R1 + tid * 4);
        m2h[hrow] = *(float*)(smem + OFF_R2 + tid * 4);
        i1h[hrow] = *(int*)(smem + OFF_RI + tid * 4);
        int c = *(int*)(smem + OFF_CT + tid * 4);
        counts[hrow] = c > CAP ? CAP : c;
        if (dcounts) dcounts[hrow] = *(int*)(smem + OFF_DC + tid * 4);  // raw (overflow detect)
    }
}

// ---- finalize: softmax over candidate lists -> quantized, loss; merge top2
__global__ __launch_bounds__(256) void vq_finalize(
        const float* __restrict__ cb, const float* __restrict__ x,
        const int2* __restrict__ lists, const int* __restrict__ counts,
        float* __restrict__ m1h, float* __restrict__ m2h, int* __restrict__ i1h,
        float* __restrict__ out_q, float* __restrict__ out_loss) {
    __shared__ int2 ebuf[4][2 * CAP];
    int w = threadIdx.x >> 6, lane = threadIdx.x & 63;
    int row = blockIdx.x * 4 + w;
    int n0 = counts[row];      if (n0 > CAP) n0 = CAP;
    int n1 = counts[B + row];  if (n1 > CAP) n1 = CAP;
    int n = n0 + n1;
    if (lane < n0) ebuf[w][lane] = lists[(size_t)row * CAP + lane];
    if (lane < n1) ebuf[w][n0 + lane] = lists[(size_t)(B + row) * CAP + lane];
    __syncthreads();
    float m = -INFINITY;
    for (int e = lane; e < n; e += 64) m = fmaxf(m, __int_as_float(ebuf[w][e].x));
    #pragma unroll
    for (int off = 1; off < 64; off <<= 1) m = fmaxf(m, __shfl_xor(m, off));
    float denom = 0.f;
    for (int e = lane; e < n; e += 64) denom += __expf(__int_as_float(ebuf[w][e].x) - m);
    #pragma unroll
    for (int off = 1; off < 64; off <<= 1) denom += __shfl_xor(denom, off);
    float q[8] = {0.f, 0.f, 0.f, 0.f, 0.f, 0.f, 0.f, 0.f};
    for (int e = 0; e < n; ++e) {
        int2 ent = ebuf[w][e];
        float wgt = __expf(__int_as_float(ent.x) - m);
        const float4* c4 = reinterpret_cast<const float4*>(cb + (size_t)ent.y * D + lane * 8);
        float4 c0 = c4[0], c1 = c4[1];
        q[0] += wgt * c0.x; q[1] += wgt * c0.y; q[2] += wgt * c0.z; q[3] += wgt * c0.w;
        q[4] += wgt * c1.x; q[5] += wgt * c1.y; q[6] += wgt * c1.z; q[7] += wgt * c1.w;
    }
    float inv = 1.f / denom;
    const float4* x4 = reinterpret_cast<const float4*>(x + (size_t)row * D + lane * 8);
    float4 xa = x4[0], xb = x4[1];
    float xs[8] = {xa.x, xa.y, xa.z, xa.w, xb.x, xb.y, xb.z, xb.w};
    float ls = 0.f;
    #pragma unroll
    for (int k = 0; k < 8; ++k) {
        q[k] *= inv;
        float dlt = xs[k] - q[k];
        ls += dlt * dlt;
    }
    float4 q0 = {q[0], q[1], q[2], q[3]}, q1 = {q[4], q[5], q[6], q[7]};
    float4* o = reinterpret_cast<float4*>(out_q + (size_t)row * D + lane * 8);
    o[0] = q0; o[1] = q1;
    #pragma unroll
    for (int off = 1; off < 64; off <<= 1) ls += __shfl_xor(ls, off);
    if (lane == 0) {
        out_loss[row] = 1.25f * ls;
        // merge half top-2 (half0 indices < half1 indices; ties keep half0)
        float a1 = m1h[row], a2 = m2h[row]; int ai = i1h[row];
        float b1 = m1h[B + row], b2 = m2h[B + row]; int bi = i1h[B + row];
        float mm1, mm2; int mi;
        if (b1 < a1) { mm1 = b1; mi = bi; mm2 = fminf(a1, b2); }
        else         { mm1 = a1; mi = ai; mm2 = fminf(b1, a2); }
        m1h[row] = mm1; m2h[row] = mm2; i1h[row] = mi;
    }
}

// ---- candidate-based f64 argmin recheck (one wave per row) --------------
__global__ __launch_bounds__(256) void argmin_fix2(
        const float* __restrict__ x, const float* __restrict__ cb,
        const float* __restrict__ m1h, const float* __restrict__ m2h,
        const int* __restrict__ i1h,
        const int* __restrict__ dcounts, const int* __restrict__ dlists,
        float* __restrict__ out_ind) {
    int w = threadIdx.x >> 6, lane = threadIdx.x & 63;
    int row = blockIdx.x * 4 + w;
    if (m2h[row] - m1h[row] >= DELTA) {
        if (lane == 0) out_ind[row] = (float)i1h[row];
        return;
    }
    // x row in f64 registers: lane covers d = lane*8 .. lane*8+7
    const float4* x4 = reinterpret_cast<const float4*>(x + (size_t)row * D) + lane * 2;
    float4 xa = x4[0], xb = x4[1];
    double xd[8] = {(double)xa.x, (double)xa.y, (double)xa.z, (double)xa.w,
                    (double)xb.x, (double)xb.y, (double)xb.z, (double)xb.w};
    double bestv = 1e300; int besti = 0x7fffffff;

    auto evalCode = [&](int n) {
        const float4* c4 = reinterpret_cast<const float4*>(cb + (size_t)n * D) + lane * 2;
        float4 ca = c4[0], cbv = c4[1];
        double cd[8] = {(double)ca.x, (double)ca.y, (double)ca.z, (double)ca.w,
                        (double)cbv.x, (double)cbv.y, (double)cbv.z, (double)cbv.w};
        double s = 0.0;
        #pragma unroll
        for (int k = 0; k < 8; ++k) {
            double dlt = xd[k] - cd[k];
            s = fma(dlt, dlt, s);
        }
        #pragma unroll
        for (int off = 1; off < 64; off <<= 1) s += __shfl_xor(s, off);
        if (s < bestv || (s == bestv && n < besti)) { bestv = s; besti = n; }
    };

    int n0 = dcounts[row], n1 = dcounts[B + row];
    if (n0 <= DCAP && n1 <= DCAP) {
        for (int e = 0; e < n0; ++e) evalCode(dlists[(size_t)row * DCAP + e]);
        for (int e = 0; e < n1; ++e) evalCode(dlists[(size_t)(B + row) * DCAP + e]);
    } else {
        for (int n = 0; n < N; ++n) evalCode(n);   // rare overflow fallback
    }
    if (lane == 0) out_ind[row] = (float)besti;
}

// ======================= FALLBACK PATH (round-1, passing) =================
constexpr int ROWS = 16;
constexpr int NT   = 256;
constexpr int DT   = 16;

__global__ __launch_bounds__(256) void prep_norms(const float* __restrict__ x,
                                                  const float* __restrict__ cb,
                                                  float* __restrict__ cnorm,
                                                  float* __restrict__ xnorm) {
    int wave = threadIdx.x >> 6, lane = threadIdx.x & 63;
    int v = blockIdx.x * 4 + wave;
    const float* src;
    float* dst;
    if (v < N) { src = cb + (size_t)v * D; dst = cnorm + v; }
    else       { int b = v - N; if (b >= B) return; src = x + (size_t)b * D; dst = xnorm + b; }
    const float4* s4 = reinterpret_cast<const float4*>(src) + lane * 2;
    float4 a = s4[0], c = s4[1];
    float s = a.x*a.x + a.y*a.y + a.z*a.z + a.w*a.w
            + c.x*c.x + c.y*c.y + c.z*c.z + c.w*c.w;
    #pragma unroll
    for (int off = 1; off < 64; off <<= 1) s += __shfl_xor(s, off);
    if (lane == 0) *dst = s;
}

__global__ __launch_bounds__(256) void vq_main(const float* __restrict__ x,
        const float* __restrict__ cb, const float* __restrict__ u,
        const float* __restrict__ cnorm, const float* __restrict__ xnorm,
        float* __restrict__ out_q, float* __restrict__ out_loss,
        float* __restrict__ m1w, float* __restrict__ m2w, int* __restrict__ i1w) {

    __shared__ float xs[ROWS][D];
    __shared__ float ct[DT][NT];

    const int tid  = threadIdx.x;
    const int wave = tid >> 6, lane = tid & 63;
    const int rbase = blockIdx.x * ROWS;
    const int wrow  = rbase + wave * 4;

    for (int i = tid; i < ROWS * (D / 4); i += 256)
        reinterpret_cast<float4*>(xs)[i] =
            reinterpret_cast<const float4*>(x + (size_t)rbase * D)[i];
    __syncthreads();

    float xn[4];
    #pragma unroll
    for (int r = 0; r < 4; ++r) xn[r] = xnorm[wrow + r];

    float m[4], denom[4], acc[4][8];
    float am1[4], am2[4]; int ai1[4];
    #pragma unroll
    for (int r = 0; r < 4; ++r) {
        m[r] = -INFINITY; denom[r] = 0.f;
        am1[r] = INFINITY; am2[r] = INFINITY; ai1[r] = 0;
        #pragma unroll
        for (int k = 0; k < 8; ++k) acc[r][k] = 0.f;
    }

    for (int nb = 0; nb < N; nb += NT) {
        float S[4][4];
        #pragma unroll
        for (int r = 0; r < 4; ++r)
            #pragma unroll
            for (int j = 0; j < 4; ++j) S[r][j] = 0.f;

        for (int db = 0; db < D; db += DT) {
            __syncthreads();
            {
                const float4* src = reinterpret_cast<const float4*>(
                        cb + (size_t)(nb + tid) * D + db);
                float4 a0 = src[0], a1 = src[1], a2 = src[2], a3 = src[3];
                ct[ 0][tid]=a0.x; ct[ 1][tid]=a0.y; ct[ 2][tid]=a0.z; ct[ 3][tid]=a0.w;
                ct[ 4][tid]=a1.x; ct[ 5][tid]=a1.y; ct[ 6][tid]=a1.z; ct[ 7][tid]=a1.w;
                ct[ 8][tid]=a2.x; ct[ 9][tid]=a2.y; ct[10][tid]=a2.z; ct[11][tid]=a2.w;
                ct[12][tid]=a3.x; ct[13][tid]=a3.y; ct[14][tid]=a3.z; ct[15][tid]=a3.w;
            }
            __syncthreads();
            #pragma unroll
            for (int dq = 0; dq < DT / 4; ++dq) {
                float creg[4][4];
                #pragma unroll
                for (int k = 0; k < 4; ++k) {
                    float4 cv = *reinterpret_cast<const float4*>(&ct[dq*4 + k][4*lane]);
                    creg[k][0]=cv.x; creg[k][1]=cv.y; creg[k][2]=cv.z; creg[k][3]=cv.w;
                }
                #pragma unroll
                for (int r = 0; r < 4; ++r) {
                    float4 xv = *reinterpret_cast<const float4*>(&xs[wave*4 + r][db + dq*4]);
                    float xr[4] = {xv.x, xv.y, xv.z, xv.w};
                    #pragma unroll
                    for (int k = 0; k < 4; ++k)
                        #pragma unroll
                        for (int j = 0; j < 4; ++j)
                            S[r][j] = fmaf(xr[k], creg[k][j], S[r][j]);
                }
            }
        }

        float4 cn4 = *reinterpret_cast<const float4*>(&cnorm[nb + 4*lane]);
        float cn[4] = {cn4.x, cn4.y, cn4.z, cn4.w};

        float logit[4][4], dist[4][4];
        #pragma unroll
        for (int r = 0; r < 4; ++r) {
            float4 u4 = *reinterpret_cast<const float4*>(
                    &u[(size_t)(wrow + r) * N + nb + 4*lane]);
            float uu[4] = {u4.x, u4.y, u4.z, u4.w};
            #pragma unroll
            for (int j = 0; j < 4; ++j) {
                float ds = xn[r] - 2.f * S[r][j] + cn[j];
                float g  = -logf(-logf(uu[j] + EPSF) + EPSF);
                dist[r][j]  = ds;
                logit[r][j] = g - ds;
            }
        }

        #pragma unroll
        for (int r = 0; r < 4; ++r) {
            float l1 = INFINITY, l2 = INFINITY; int li = 0;
            #pragma unroll
            for (int j = 0; j < 4; ++j) {
                float dv = dist[r][j]; int idx = nb + 4*lane + j;
                if (dv < l1)      { l2 = l1; l1 = dv; li = idx; }
                else if (dv < l2) { l2 = dv; }
            }
            #pragma unroll
            for (int off = 1; off < 64; off <<= 1) {
                float o1 = __shfl_xor(l1, off), o2 = __shfl_xor(l2, off);
                int   oi = __shfl_xor(li, off);
                if (o1 < l1 || (o1 == l1 && oi < li)) { l2 = fminf(l1, o2); l1 = o1; li = oi; }
                else                                  { l2 = fminf(o1, l2); }
            }
            if (l1 < am1[r] || (l1 == am1[r] && li < ai1[r])) {
                am2[r] = fminf(am1[r], l2); am1[r] = l1; ai1[r] = li;
            } else {
                am2[r] = fminf(am2[r], l1);
            }

            float lm = fmaxf(fmaxf(logit[r][0], logit[r][1]),
                             fmaxf(logit[r][2], logit[r][3]));
            #pragma unroll
            for (int off = 1; off < 64; off <<= 1) lm = fmaxf(lm, __shfl_xor(lm, off));
            if (lm > m[r]) {
                float s = expf(m[r] - lm);
                denom[r] *= s;
                #pragma unroll
                for (int k = 0; k < 8; ++k) acc[r][k] *= s;
                m[r] = lm;
            }

            float wv[4];
            #pragma unroll
            for (int j = 0; j < 4; ++j) {
                float e = logit[r][j] - m[r];
                bool act = e > -SKIP;
                wv[j] = act ? expf(e) : 0.f;
                denom[r] += wv[j];
            }
            #pragma unroll
            for (int j = 0; j < 4; ++j) {
                unsigned long long mk = __ballot(wv[j] > 0.f);
                while (mk) {
                    int L = __ffsll((unsigned long long)mk) - 1;
                    mk &= mk - 1;
                    float wb = __shfl(wv[j], L);
                    int nstar = nb + 4*L + j;
                    const float4* crow = reinterpret_cast<const float4*>(
                            cb + (size_t)nstar * D + 8*lane);
                    float4 c0 = crow[0], c1 = crow[1];
                    acc[r][0] = fmaf(wb, c0.x, acc[r][0]);
                    acc[r][1] = fmaf(wb, c0.y, acc[r][1]);
                    acc[r][2] = fmaf(wb, c0.z, acc[r][2]);
                    acc[r][3] = fmaf(wb, c0.w, acc[r][3]);
                    acc[r][4] = fmaf(wb, c1.x, acc[r][4]);
                    acc[r][5] = fmaf(wb, c1.y, acc[r][5]);
                    acc[r][6] = fmaf(wb, c1.z, acc[r][6]);
                    acc[r][7] = fmaf(wb, c1.w, acc[r][7]);
                }
            }
        }
    }

    #pragma unroll
    for (int r = 0; r < 4; ++r) {
        float dn = denom[r];
        #pragma unroll
        for (int off = 1; off < 64; off <<= 1) dn += __shfl_xor(dn, off);
        float inv = 1.f / dn;
        int row = wrow + r;
        float q[8]; float ls = 0.f;
        #pragma unroll
        for (int k = 0; k < 8; ++k) {
            q[k] = acc[r][k] * inv;
            float dlt = xs[wave*4 + r][8*lane + k] - q[k];
            ls += dlt * dlt;
        }
        float4 q0 = {q[0], q[1], q[2], q[3]}, q1 = {q[4], q[5], q[6], q[7]};
        float4* o = reinterpret_cast<float4*>(out_q + (size_t)row * D + 8*lane);
        o[0] = q0; o[1] = q1;
        #pragma unroll
        for (int off = 1; off < 64; off <<= 1) ls += __shfl_xor(ls, off);
        if (lane == 0) {
            out_loss[row] = 1.25f * ls;
            m1w[row] = am1[r]; m2w[row] = am2[r]; i1w[row] = ai1[r];
        }
    }
}

// ---- full-scan f64 argmin recheck (fallback paths only) ------------------
__global__ __launch_bounds__(256) void argmin_fix(const float* __restrict__ x,
        const float* __restrict__ cb, const float* __restrict__ m1w,
        const float* __restrict__ m2w, const int* __restrict__ i1w,
        float* __restrict__ out_ind) {
    int b = blockIdx.x, tid = threadIdx.x;
    if (m2w[b] - m1w[b] >= DELTA) {
        if (tid == 0) out_ind[b] = (float)i1w[b];
        return;
    }
    __shared__ double xsd[D];
    for (int i = tid; i < D; i += 256) xsd[i] = (double)x[(size_t)b * D + i];
    __syncthreads();
    double xn = 0.0;
    for (int d = 0; d < D; ++d) xn += xsd[d] * xsd[d];

    double bestv = 1e300; int besti = N;
    for (int n = tid; n < N; n += 256) {
        const float* c = cb + (size_t)n * D;
        double d0 = 0.0, d1v = 0.0, c0 = 0.0, c1v = 0.0;
        for (int d = 0; d < D; d += 2) {
            double ca = (double)c[d], cbv = (double)c[d + 1];
            d0 += xsd[d] * ca;  c0 += ca * ca;
            d1v += xsd[d + 1] * cbv; c1v += cbv * cbv;
        }
        double dv = xn - 2.0 * (d0 + d1v) + (c0 + c1v);
        if (dv < bestv || (dv == bestv && n < besti)) { bestv = dv; besti = n; }
    }
    __shared__ double rv[256]; __shared__ int ri[256];
    rv[tid] = bestv; ri[tid] = besti;
    __syncthreads();
    for (int s = 128; s > 0; s >>= 1) {
        if (tid < s) {
            if (rv[tid+s] < rv[tid] || (rv[tid+s] == rv[tid] && ri[tid+s] < ri[tid])) {
                rv[tid] = rv[tid+s]; ri[tid] = ri[tid+s];
            }
        }
        __syncthreads();
    }
    if (tid == 0) out_ind[b] = (float)ri[0];
}

// ---------------- host launch --------------------------------------------
extern "C" void kernel_launch(void* const* d_in, const int* in_sizes, int n_in,
                              void* d_out, int out_size, void* d_ws, size_t ws_size,
                              hipStream_t stream) {
    const float* x  = (const float*)d_in[0];
    const float* cb = (const float*)d_in[1];
    const float* u  = (const float*)d_in[2];
    float* out      = (float*)d_out;
    float* out_q    = out;
    float* out_ind  = out + (size_t)B * D;
    float* out_loss = out_ind + B;

    // fast-path workspace layout (bytes)
    const size_t O_XH = 0;
    const size_t O_XL = O_XH + (size_t)B * D * 2;
    const size_t O_CH = O_XL + (size_t)B * D * 2;
    const size_t O_CL = O_CH + (size_t)N * D * 2;
    const size_t O_CN = O_CL + (size_t)N * D * 2;
    const size_t O_XN = O_CN + (size_t)N * 4;
    const size_t O_M1 = O_XN + (size_t)B * 4;
    const size_t O_M2 = O_M1 + (size_t)2 * B * 4;
    const size_t O_I1 = O_M2 + (size_t)2 * B * 4;
    const size_t O_CT = O_I1 + (size_t)2 * B * 4;
    const size_t O_LS = O_CT + (size_t)2 * B * 4;
    const size_t O_DC = O_LS + (size_t)2 * B * CAP * 8;
    const size_t O_DL = O_DC + (size_t)2 * B * 4;
    const size_t NEED2 = O_DL + (size_t)2 * B * DCAP * 4;   // ~43.4 MB
    const size_t NEED1 = O_DC;                               // round-2 layout

    if (ws_size >= NEED1) {
        char* w8 = (char*)d_ws;
        unsigned short* xh = (unsigned short*)(w8 + O_XH);
        unsigned short* xl = (unsigned short*)(w8 + O_XL);
        unsigned short* ch = (unsigned short*)(w8 + O_CH);
        unsigned short* cl = (unsigned short*)(w8 + O_CL);
        float* cnorm = (float*)(w8 + O_CN);
        float* xnorm = (float*)(w8 + O_XN);
        float* m1h   = (float*)(w8 + O_M1);
        float* m2h   = (float*)(w8 + O_M2);
        int*   i1h   = (int*)(w8 + O_I1);
        int*   counts= (int*)(w8 + O_CT);
        int2*  lists = (int2*)(w8 + O_LS);
        bool  deep   = (ws_size >= NEED2);
        int*  dcounts= deep ? (int*)(w8 + O_DC) : nullptr;
        int*  dlists = deep ? (int*)(w8 + O_DL) : nullptr;

        hipLaunchKernelGGL(vq_prep, dim3((N + B) / 4), dim3(256), 0, stream,
                           x, cb, xh, xl, ch, cl, cnorm, xnorm, counts, dcounts);
        hipLaunchKernelGGL(vq_mfma, dim3(256), dim3(512), 0, stream,
                           xh, xl, ch, cl, cnorm, xnorm, u, lists, counts,
                           dlists, dcounts, m1h, m2h, i1h);
        hipLaunchKernelGGL(vq_finalize, dim3(B / 4), dim3(256), 0, stream,
                           cb, x, lists, counts, m1h, m2h, i1h, out_q, out_loss);
        if (deep) {
            hipLaunchKernelGGL(argmin_fix2, dim3(B / 4), dim3(256), 0, stream,
                               x, cb, m1h, m2h, i1h, dcounts, dlists, out_ind);
        } else {
            hipLaunchKernelGGL(argmin_fix, dim3(B), dim3(256), 0, stream,
                               x, cb, m1h, m2h, i1h, out_ind);
        }
    } else {
        float* ws    = (float*)d_ws;
        float* cnorm = ws;
        float* xnorm = ws + N;
        float* m1w   = xnorm + B;
        float* m2w   = m1w + B;
        int*   i1w   = (int*)(m2w + B);

        hipLaunchKernelGGL(prep_norms, dim3((N + B) / 4), dim3(256), 0, stream,
                           x, cb, cnorm, xnorm);
        hipLaunchKernelGGL(vq_main, dim3(B / ROWS), dim3(256), 0, stream,
                           x, cb, u, cnorm, xnorm, out_q, out_loss, m1w, m2w, i1w);
        hipLaunchKernelGGL(argmin_fix, dim3(B), dim3(256), 0, stream,
                           x, cb, m1w, m2w, i1w, out_ind);
    }
}